// Round 8
// baseline (414.642 us; speedup 1.0000x reference)
//
#include <hip/hip_runtime.h>

#define HH 192
#define WW 192
#define HWPIX (HH * WW)
#define ROWPX 20             // padded LDS row: iw' = gw-(w0-2) in 0..19, reads use 1..18
#define PLANE 5824           // 18*20*16 = 5760 + 64 pad (2-way plane pairing)
#define CHUNKB (4 * PLANE)   // 23296 B per 32c chunk

typedef __attribute__((ext_vector_type(8))) short bf16x8;
typedef __attribute__((ext_vector_type(4))) float f32x4;
typedef __attribute__((ext_vector_type(2))) float f32x2;
typedef __attribute__((ext_vector_type(4))) unsigned int u32x4;

__device__ __forceinline__ unsigned f2bf(float f) {
    unsigned u = __builtin_bit_cast(unsigned, f);
    return (u + 0x7FFFu + ((u >> 16) & 1u)) >> 16;
}

__device__ __forceinline__ unsigned cvtpk(float lo, float hi) {
    unsigned r;
    asm("v_cvt_pk_bf16_f32 %0, %1, %2" : "=v"(r) : "v"(lo), "v"(hi));
    return r;
}

// ---------------- weight fusion (round-5/7 layout, proven) ----------------
// frag = ((cc*3 + kw)*2 + mi)*12 + kh*4 + mo ; within frag: ln*8 + j
// mi=o>>6, mo=(o>>4)&3, ln=((c>>3)&3)*16+(o&15), j=c&7, cc=c>>5
__global__ void fuse_weights(const float* __restrict__ wsq, const float* __restrict__ wv,
                             const float* __restrict__ whr, const float* __restrict__ w19,
                             const float* __restrict__ w37, unsigned short* __restrict__ wbuf) {
    int idx = blockIdx.x * 256 + threadIdx.x;
    if (idx >= 128 * 128 * 9) return;
    int o = idx / 1152;
    int r = idx - o * 1152;
    int c = r / 9;
    int tap = r - c * 9;
    int kh = tap / 3, kw = tap - kh * 3;
    float v = wsq[((o * 128 + c) * 3 + kh) * 3 + kw];
    if (kw == 1) v += wv[(o * 128 + c) * 3 + kh];
    if (kh == 1) v += whr[(o * 128 + c) * 3 + kw];
    if (kh == kw) v += w19[((o * 128 + c) * 3 + kh) * 3 + kw];
    if (kh + kw == 2) v += w37[((o * 128 + c) * 3 + kh) * 3 + kw];
    int cc = c >> 5;
    int mi = o >> 6, mo = (o >> 4) & 3;
    int ln = ((c >> 3) & 3) * 16 + (o & 15);
    int j = c & 7;
    int frag = ((cc * 3 + kw) * 2 + mi) * 12 + kh * 4 + mo;
    wbuf[(size_t)frag * 512 + ln * 8 + j] = (unsigned short)f2bf(v);
}

// ---------------- single-pass conv ----------------
// Block: 16x16 out px, 128 o, 4 waves = (mi: o-half, ni: row-half).
// Staging: thread owns a pixel-PAIR per item: 8x global_load_dwordx2
// (8B-aligned: gw base = w0-2+2q), v_cvt_pk_bf16_f32 pack, one
// ds_write_b128 per px. LDS layout per c-octet plane: px at
// hi*128 + ((px&7)^(hi&7))*16  (XOR swizzle, same on read+write:
// writes at lane-stride 32B and reads both 2-way max = free).
// 720 items/chunk in 3 rounds interleaved between kw passes (T14).
__global__ __launch_bounds__(256, 2) void conv1(const float* __restrict__ x,
                                                const unsigned short* __restrict__ wbuf,
                                                float* __restrict__ out) {
    __shared__ __align__(1024) unsigned char lds[2 * CHUNKB];
    const int t = threadIdx.x, l = t & 63, wvid = t >> 6;
    const int mi = wvid >> 1, ni = wvid & 1, l15 = l & 15, l4 = l >> 4;

    // XCD-chunked bijective swizzle: 2304 = 8 x 288; 288/XCD = 2 full batches.
    int id = (int)blockIdx.x;
    int id2 = (id & 7) * 288 + (id >> 3);
    int b = id2 / 144;
    int rem = id2 - b * 144;
    int by = rem / 12, bx = rem - by * 12;
    const int h0 = by * 16, w0 = bx * 16;

    const float* __restrict__ xb = x + (size_t)b * (128 * HWPIX);

    f32x4 acc[4][8];
    const f32x4 zero = {0.f, 0.f, 0.f, 0.f};
#pragma unroll
    for (int mo = 0; mo < 4; ++mo)
#pragma unroll
        for (int np = 0; np < 8; ++np) acc[mo][np] = zero;

    f32x2 svA[8], svB[8];

    // item in 0..719: s = item/180 (c-octet), pr = item%180: row = pr/10,
    // pq = pr%10 -> pixel pair iw' = 2pq,2pq+1 ; gw = w0-2+2pq+e.
#define LOADH(CC, R, SV)                                                                 \
    if ((R) < 2 || t < 208) {                                                            \
        int item = t + 256 * (R);                                                        \
        int s = item / 180;                                                              \
        int pr = item - s * 180;                                                         \
        int row = pr / 10;                                                               \
        int pq = pr - row * 10;                                                          \
        int gh = h0 - 1 + row;                                                           \
        int ghc = min(max(gh, 0), HH - 1);                                               \
        int gwb = w0 - 2 + 2 * pq;                                                       \
        int gwc = min(max(gwb, 0), WW - 2);                                              \
        const float* p = xb + (size_t)((CC) * 32 + s * 8) * HWPIX + ghc * WW + gwc;      \
        _Pragma("unroll") for (int j = 0; j < 8; ++j)                                    \
            SV[j] = *(const f32x2*)(p + (size_t)j * HWPIX);                              \
    }

#define WRITEH(R, BB, SV)                                                                \
    if ((R) < 2 || t < 208) {                                                            \
        int item = t + 256 * (R);                                                        \
        int s = item / 180;                                                              \
        int pr = item - s * 180;                                                         \
        int row = pr / 10;                                                               \
        int pq = pr - row * 10;                                                          \
        int gh = h0 - 1 + row;                                                           \
        bool hok = (unsigned)gh < (unsigned)HH;                                          \
        int gwb = w0 - 2 + 2 * pq;                                                       \
        int px0 = row * ROWPX + 2 * pq;                                                  \
        _Pragma("unroll") for (int e = 0; e < 2; ++e) {                                  \
            bool ok = hok && ((unsigned)(gwb + e) < (unsigned)WW);                       \
            u32x4 pk;                                                                    \
            _Pragma("unroll") for (int q = 0; q < 4; ++q) {                              \
                unsigned v = cvtpk(SV[2 * q][e], SV[2 * q + 1][e]);                      \
                pk[q] = ok ? v : 0u;                                                     \
            }                                                                            \
            int px = px0 + e;                                                            \
            int hi = px >> 3;                                                            \
            int sl = (px & 7) ^ (hi & 7);                                                \
            *(u32x4*)(lds + (BB) + s * PLANE + hi * 128 + sl * 16) = pk;                 \
        }                                                                                \
    }

#define KWPASS(KW)                                                                       \
    {                                                                                    \
        const unsigned short* wp =                                                       \
            wbuf + (size_t)(((cc * 3 + (KW)) * 2 + mi) * 12) * 512 + l * 8;              \
        bf16x8 a[12];                                                                    \
        _Pragma("unroll") for (int f = 0; f < 12; ++f)                                   \
            a[f] = *(const bf16x8*)(wp + f * 512);                                       \
        __builtin_amdgcn_s_setprio(1);                                                   \
        _Pragma("unroll") for (int rr = 0; rr < 10; ++rr) {                              \
            int px = (ni * 8 + rr) * ROWPX + (KW) + 1 + l15;                             \
            int hi = px >> 3;                                                            \
            int addr = bb + l4 * PLANE + hi * 128 + ((px & 7) ^ (hi & 7)) * 16;          \
            bf16x8 bf = *(const bf16x8*)(lds + addr);                                    \
            _Pragma("unroll") for (int kh = 0; kh < 3; ++kh) {                           \
                const int np = rr - kh;                                                  \
                if (np >= 0 && np < 8) {                                                 \
                    _Pragma("unroll") for (int mo = 0; mo < 4; ++mo)                     \
                        acc[mo][np] = __builtin_amdgcn_mfma_f32_16x16x32_bf16(           \
                            a[kh * 4 + mo], bf, acc[mo][np], 0, 0, 0);                   \
                }                                                                        \
            }                                                                            \
        }                                                                                \
        __builtin_amdgcn_s_setprio(0);                                                   \
    }

    // prologue: stage chunk 0 into buffer 0
    LOADH(0, 0, svA)
    WRITEH(0, 0, svA)
    LOADH(0, 1, svA)
    WRITEH(1, 0, svA)
    LOADH(0, 2, svA)
    WRITEH(2, 0, svA)
    __syncthreads();

    int bb = 0;
#pragma unroll 1
    for (int cc = 0; cc < 4; ++cc) {
        if (cc < 3) { LOADH(cc + 1, 0, svA) }
        KWPASS(0)
        if (cc < 3) {
            LOADH(cc + 1, 1, svB)
            WRITEH(0, bb ^ CHUNKB, svA)
        }
        KWPASS(1)
        if (cc < 3) {
            LOADH(cc + 1, 2, svA)
            WRITEH(1, bb ^ CHUNKB, svB)
        }
        KWPASS(2)
        if (cc < 3) { WRITEH(2, bb ^ CHUNKB, svA) }
        __syncthreads();
        bb ^= CHUNKB;
    }

    // epilogue: D row=(l>>4)*4+j -> o_low, col=l&15 -> w  (proven r5/r7)
    float* __restrict__ ob = out + (size_t)b * (128 * HWPIX) + (size_t)h0 * WW + w0 + l15;
#pragma unroll
    for (int mo = 0; mo < 4; ++mo) {
#pragma unroll
        for (int j = 0; j < 4; ++j) {
            int o = mi * 64 + mo * 16 + l4 * 4 + j;
            float* op = ob + (size_t)o * HWPIX;
#pragma unroll
            for (int np = 0; np < 8; ++np)
                op[(ni * 8 + np) * WW] = acc[mo][np][j];
        }
    }
}

extern "C" void kernel_launch(void* const* d_in, const int* in_sizes, int n_in,
                              void* d_out, int out_size, void* d_ws, size_t ws_size,
                              hipStream_t stream) {
    const float* x   = (const float*)d_in[0];
    const float* wsq = (const float*)d_in[1];
    const float* wvv = (const float*)d_in[2];
    const float* wh  = (const float*)d_in[3];
    const float* w19 = (const float*)d_in[4];
    const float* w37 = (const float*)d_in[5];

    unsigned short* wbuf = (unsigned short*)d_ws;  // 294,912 B

    fuse_weights<<<576, 256, 0, stream>>>(wsq, wvv, wh, w19, w37, wbuf);
    conv1<<<2304, 256, 0, stream>>>(x, wbuf, (float*)d_out);
}

// Round 9
// 316.244 us; speedup vs baseline: 1.3111x; 1.3111x over previous
//
#include <hip/hip_runtime.h>

#define HH 192
#define WW 192
#define HWPIX (HH * WW)

typedef __attribute__((ext_vector_type(8))) short bf16x8;
typedef __attribute__((ext_vector_type(4))) float f32x4;
typedef __attribute__((ext_vector_type(4))) unsigned int u32x4;

__device__ __forceinline__ unsigned f2bf(float f) {
    unsigned u = __builtin_bit_cast(unsigned, f);
    return (u + 0x7FFFu + ((u >> 16) & 1u)) >> 16;
}

__device__ __forceinline__ unsigned cvtpk(float lo, float hi) {
    unsigned r;
    asm("v_cvt_pk_bf16_f32 %0, %1, %2" : "=v"(r) : "v"(lo), "v"(hi));
    return r;
}

// ---------------- weight fusion ----------------
// frag = ((cc*3 + kw)*3 + kh)*8 + ow ; within frag: ln*8 + j  (shorts)
// ow=o>>4, ln=((c>>3)&3)*16+(o&15), j=c&7, cc=c>>5
__global__ void fuse_weights(const float* __restrict__ wsq, const float* __restrict__ wv,
                             const float* __restrict__ whr, const float* __restrict__ w19,
                             const float* __restrict__ w37, unsigned short* __restrict__ wbuf) {
    int idx = blockIdx.x * 256 + threadIdx.x;
    if (idx >= 128 * 128 * 9) return;
    int o = idx / 1152;
    int r = idx - o * 1152;
    int c = r / 9;
    int tap = r - c * 9;
    int kh = tap / 3, kw = tap - kh * 3;
    float v = wsq[((o * 128 + c) * 3 + kh) * 3 + kw];
    if (kw == 1) v += wv[(o * 128 + c) * 3 + kh];
    if (kh == 1) v += whr[(o * 128 + c) * 3 + kw];
    if (kh == kw) v += w19[((o * 128 + c) * 3 + kh) * 3 + kw];
    if (kh + kw == 2) v += w37[((o * 128 + c) * 3 + kh) * 3 + kw];
    int cc = c >> 5, ow = o >> 4;
    int ln = ((c >> 3) & 3) * 16 + (o & 15);
    int j = c & 7;
    int frag = ((cc * 3 + kw) * 3 + kh) * 8 + ow;
    wbuf[(size_t)frag * 512 + ln * 8 + j] = (unsigned short)f2bf(v);
}

// ---------------- barrier-free direct-from-global conv ----------------
// Block: 16x16 out px, 128 o, 4 independent waves (ni = wave = 4-row band).
// NO LDS, NO barriers. Per iter (cc,kw) of 12: build 6 B-frags from global
// (8 coalesced dword loads each: lane l -> px w0-1+kw+l15, ch l4*8+j;
// this IS the MFMA B layout), pack via v_cvt_pk_bf16_f32 + OOB zeroing,
// then 8 ow x 12 MFMA with weight frags streamed from L2.
// Single fv buffer: pack(it) reads, then loads(it+1) overwrite (WAR in-order)
// -> loads stay in flight across the whole MFMA block, never drained to 0.
__global__ __launch_bounds__(256, 2) void convg(const float* __restrict__ x,
                                                const unsigned short* __restrict__ wbuf,
                                                float* __restrict__ out) {
    const int t = threadIdx.x, l = t & 63, ni = t >> 6;
    const int l15 = l & 15, l4 = l >> 4;

    // XCD-chunked bijective swizzle: 2304 = 8 x 288 (= 2 full batches/XCD).
    int id = (int)blockIdx.x;
    int id2 = (id & 7) * 288 + (id >> 3);
    int b = id2 / 144;
    int rem = id2 - b * 144;
    int by = rem / 12, bx = rem - by * 12;
    const int h0 = by * 16, w0 = bx * 16;

    const float* __restrict__ xb = x + (size_t)b * (128 * HWPIX);

    f32x4 acc[8][4];
    const f32x4 zero = {0.f, 0.f, 0.f, 0.f};
#pragma unroll
    for (int ow = 0; ow < 8; ++ow)
#pragma unroll
        for (int np = 0; np < 4; ++np) acc[ow][np] = zero;

    // input rows for this wave: gh = h0 + 4*ni - 1 + rid, rid 0..5
    int ghc[6], hok[6];
#pragma unroll
    for (int rid = 0; rid < 6; ++rid) {
        int gh = h0 + 4 * ni - 1 + rid;
        hok[rid] = (unsigned)gh < (unsigned)HH;
        ghc[rid] = min(max(gh, 0), HH - 1);
    }

    float fv[6][8];
    bf16x8 Bc[6];

#define LOADI(IT)                                                                        \
    {                                                                                    \
        int cc_ = (IT) / 3, kw_ = (IT) - 3 * cc_;                                        \
        int gw = w0 - 1 + kw_ + l15;                                                     \
        int gwc = min(max(gw, 0), WW - 1);                                               \
        const float* pb = xb + (size_t)(cc_ * 32 + l4 * 8) * HWPIX + gwc;                \
        _Pragma("unroll") for (int rid = 0; rid < 6; ++rid) {                            \
            const float* p = pb + ghc[rid] * WW;                                         \
            _Pragma("unroll") for (int j = 0; j < 8; ++j)                                \
                fv[rid][j] = p[(size_t)j * HWPIX];                                       \
        }                                                                                \
    }

#define PACKI(IT)                                                                        \
    {                                                                                    \
        int cc_ = (IT) / 3, kw_ = (IT) - 3 * cc_;                                        \
        (void)cc_;                                                                       \
        int gw = w0 - 1 + kw_ + l15;                                                     \
        int wok = (unsigned)gw < (unsigned)WW;                                           \
        _Pragma("unroll") for (int rid = 0; rid < 6; ++rid) {                            \
            int ok = wok & hok[rid];                                                     \
            u32x4 pk;                                                                    \
            _Pragma("unroll") for (int q = 0; q < 4; ++q) {                              \
                unsigned v = cvtpk(fv[rid][2 * q], fv[rid][2 * q + 1]);                  \
                pk[q] = ok ? v : 0u;                                                     \
            }                                                                            \
            Bc[rid] = __builtin_bit_cast(bf16x8, pk);                                    \
        }                                                                                \
    }

#define MMI(IT)                                                                          \
    {                                                                                    \
        int cc_ = (IT) / 3, kw_ = (IT) - 3 * cc_;                                        \
        const unsigned short* wp =                                                       \
            wbuf + (size_t)((cc_ * 3 + kw_) * 3) * 8 * 512 + l * 8;                      \
        _Pragma("unroll") for (int ow = 0; ow < 8; ++ow) {                               \
            bf16x8 a0 = *(const bf16x8*)(wp + (0 * 8 + ow) * 512);                       \
            bf16x8 a1 = *(const bf16x8*)(wp + (1 * 8 + ow) * 512);                       \
            bf16x8 a2 = *(const bf16x8*)(wp + (2 * 8 + ow) * 512);                       \
            _Pragma("unroll") for (int np = 0; np < 4; ++np)                             \
                acc[ow][np] = __builtin_amdgcn_mfma_f32_16x16x32_bf16(                   \
                    a0, Bc[np + 0], acc[ow][np], 0, 0, 0);                               \
            _Pragma("unroll") for (int np = 0; np < 4; ++np)                             \
                acc[ow][np] = __builtin_amdgcn_mfma_f32_16x16x32_bf16(                   \
                    a1, Bc[np + 1], acc[ow][np], 0, 0, 0);                               \
            _Pragma("unroll") for (int np = 0; np < 4; ++np)                             \
                acc[ow][np] = __builtin_amdgcn_mfma_f32_16x16x32_bf16(                   \
                    a2, Bc[np + 2], acc[ow][np], 0, 0, 0);                               \
        }                                                                                \
    }

    LOADI(0)
#pragma unroll 1
    for (int it = 0; it < 12; ++it) {
        PACKI(it)                      // consume fv (loads landed ~1 MFMA-block ago)
        int itn = it < 11 ? it + 1 : 11;
        LOADI(itn)                     // refill fv; stays in flight across MFMA
        MMI(it)
    }

    // epilogue: D row=(l>>4)*4+j -> o, col=l&15 -> w; wave's rows = 4*ni+np
    float* __restrict__ ob =
        out + (size_t)b * (128 * HWPIX) + (size_t)(h0 + 4 * ni) * WW + w0 + l15;
#pragma unroll
    for (int ow = 0; ow < 8; ++ow) {
#pragma unroll
        for (int j = 0; j < 4; ++j) {
            int o = ow * 16 + l4 * 4 + j;
            float* op = ob + (size_t)o * HWPIX;
#pragma unroll
            for (int np = 0; np < 4; ++np)
                op[np * WW] = acc[ow][np][j];
        }
    }
}

extern "C" void kernel_launch(void* const* d_in, const int* in_sizes, int n_in,
                              void* d_out, int out_size, void* d_ws, size_t ws_size,
                              hipStream_t stream) {
    const float* x   = (const float*)d_in[0];
    const float* wsq = (const float*)d_in[1];
    const float* wvv = (const float*)d_in[2];
    const float* wh  = (const float*)d_in[3];
    const float* w19 = (const float*)d_in[4];
    const float* w37 = (const float*)d_in[5];

    unsigned short* wbuf = (unsigned short*)d_ws;  // 294,912 B

    fuse_weights<<<576, 256, 0, stream>>>(wsq, wvv, wh, w19, w37, wbuf);
    convg<<<2304, 256, 0, stream>>>(x, wbuf, (float*)d_out);
}